// Round 1
// baseline (1654.638 us; speedup 1.0000x reference)
//
#include <hip/hip_runtime.h>

#define N_TOK 16384   // B*T = 8*2048
#define DIM   512
#define CBD   256     // codebook dim
#define CBS   8192    // codebook size

// ---------------- e_sq: ||embed_c||^2 ----------------
__global__ __launch_bounds__(256) void esq_kernel(const float* __restrict__ embed,
                                                  float* __restrict__ esq) {
    int wave = threadIdx.x >> 6, lane = threadIdx.x & 63;
    int c = (blockIdx.x << 2) + wave;
    float4 v = reinterpret_cast<const float4*>(embed + (size_t)c * CBD)[lane];
    float s = v.x * v.x + v.y * v.y + v.z * v.z + v.w * v.w;
    #pragma unroll
    for (int m = 32; m; m >>= 1) s += __shfl_xor(s, m, 64);
    if (!lane) esq[c] = s;
}

// ---------------- generic NT GEMM: C[m][n] = sum_k A[m][k]*B[n][k] + bias[n] ----------------
// BM=BN=BK=64, 256 threads, 4x4 microtile. Optional row gather on A.
template <bool GATHER>
__global__ __launch_bounds__(256) void gemm_nt(const float* __restrict__ A,
                                               const float* __restrict__ B,
                                               const float* __restrict__ bias,
                                               const int* __restrict__ gather,
                                               float* __restrict__ C,
                                               int M, int N, int K) {
    // pad to 68 floats (272B) so float4 LDS reads stay 16B-aligned, banks spread
    __shared__ __align__(16) float sA[64][68];
    __shared__ __align__(16) float sB[64][68];
    const int tid = threadIdx.x;
    const int tx = tid & 15, ty = tid >> 4;
    const int bm = blockIdx.x << 6, bn = blockIdx.y << 6;
    float acc[4][4] = {};
    for (int k0 = 0; k0 < K; k0 += 64) {
        #pragma unroll
        for (int i = 0; i < 4; ++i) {
            int f = tid + (i << 8);          // float4 slot within 64x64 tile
            int m = f >> 4;                  // tile row
            int k4 = (f & 15) << 2;          // k offset
            long arow = bm + m;
            if (GATHER) arow = gather[arow];
            float4 v = *reinterpret_cast<const float4*>(A + arow * K + k0 + k4);
            sA[k4 + 0][m] = v.x; sA[k4 + 1][m] = v.y;
            sA[k4 + 2][m] = v.z; sA[k4 + 3][m] = v.w;
            float4 w = *reinterpret_cast<const float4*>(B + (long)(bn + m) * K + k0 + k4);
            sB[k4 + 0][m] = w.x; sB[k4 + 1][m] = w.y;
            sB[k4 + 2][m] = w.z; sB[k4 + 3][m] = w.w;
        }
        __syncthreads();
        #pragma unroll
        for (int kk = 0; kk < 64; ++kk) {
            float4 a = *reinterpret_cast<const float4*>(&sA[kk][ty << 2]);
            float4 b = *reinterpret_cast<const float4*>(&sB[kk][tx << 2]);
            float av[4] = {a.x, a.y, a.z, a.w};
            float bv[4] = {b.x, b.y, b.z, b.w};
            #pragma unroll
            for (int i = 0; i < 4; ++i)
                #pragma unroll
                for (int j = 0; j < 4; ++j)
                    acc[i][j] = fmaf(av[i], bv[j], acc[i][j]);
        }
        __syncthreads();
    }
    #pragma unroll
    for (int i = 0; i < 4; ++i) {
        long m = bm + (ty << 2) + i;
        #pragma unroll
        for (int j = 0; j < 4; ++j) {
            int n = bn + (tx << 2) + j;
            C[m * N + n] = acc[i][j] + bias[n];
        }
    }
}

// ---------------- scores + argmax: argmax_c (2*z.e_c - ||e_c||^2) ----------------
// One block = 64 rows; loop all 8192 codes in 64-code tiles; K=256 in 64-chunks.
__global__ __launch_bounds__(256) void score_argmax(const float* __restrict__ z,
                                                    const float* __restrict__ embed,
                                                    const float* __restrict__ esq,
                                                    int* __restrict__ idx_out,
                                                    float* __restrict__ idx_f32) {
    __shared__ __align__(16) float sZ[64][68];
    __shared__ __align__(16) float sE[64][68];
    const int tid = threadIdx.x;
    const int tx = tid & 15, ty = tid >> 4;
    const int bm = blockIdx.x << 6;
    float best[4];
    int bidx[4];
    #pragma unroll
    for (int i = 0; i < 4; ++i) { best[i] = -3.4e38f; bidx[i] = 0; }

    for (int ct = 0; ct < CBS; ct += 64) {
        float acc[4][4] = {};
        for (int k0 = 0; k0 < CBD; k0 += 64) {
            #pragma unroll
            for (int i = 0; i < 4; ++i) {
                int f = tid + (i << 8);
                int m = f >> 4;
                int k4 = (f & 15) << 2;
                float4 v = *reinterpret_cast<const float4*>(z + (long)(bm + m) * CBD + k0 + k4);
                sZ[k4 + 0][m] = v.x; sZ[k4 + 1][m] = v.y;
                sZ[k4 + 2][m] = v.z; sZ[k4 + 3][m] = v.w;
                float4 w = *reinterpret_cast<const float4*>(embed + (long)(ct + m) * CBD + k0 + k4);
                sE[k4 + 0][m] = w.x; sE[k4 + 1][m] = w.y;
                sE[k4 + 2][m] = w.z; sE[k4 + 3][m] = w.w;
            }
            __syncthreads();
            #pragma unroll
            for (int kk = 0; kk < 64; ++kk) {
                float4 a = *reinterpret_cast<const float4*>(&sZ[kk][ty << 2]);
                float4 b = *reinterpret_cast<const float4*>(&sE[kk][tx << 2]);
                float av[4] = {a.x, a.y, a.z, a.w};
                float bv[4] = {b.x, b.y, b.z, b.w};
                #pragma unroll
                for (int i = 0; i < 4; ++i)
                    #pragma unroll
                    for (int j = 0; j < 4; ++j)
                        acc[i][j] = fmaf(av[i], bv[j], acc[i][j]);
            }
            __syncthreads();
        }
        // update running argmax (ties -> lowest index, matching jnp.argmax)
        #pragma unroll
        for (int j = 0; j < 4; ++j) {
            int c = ct + (tx << 2) + j;
            float eq = esq[c];
            #pragma unroll
            for (int i = 0; i < 4; ++i) {
                float s = 2.0f * acc[i][j] - eq;
                if (s > best[i] || (s == best[i] && c < bidx[i])) { best[i] = s; bidx[i] = c; }
            }
        }
    }
    // reduce across the 16 tx lanes (contiguous within a wave)
    #pragma unroll
    for (int i = 0; i < 4; ++i) {
        float b = best[i];
        int bi = bidx[i];
        #pragma unroll
        for (int m = 1; m < 16; m <<= 1) {
            float ob = __shfl_xor(b, m, 64);
            int oi = __shfl_xor(bi, m, 64);
            if (ob > b || (ob == b && oi < bi)) { b = ob; bi = oi; }
        }
        if (tx == 0) {
            int row = bm + (ty << 2) + i;
            idx_out[row] = bi;
            idx_f32[row] = (float)bi;
        }
    }
}

extern "C" void kernel_launch(void* const* d_in, const int* in_sizes, int n_in,
                              void* d_out, int out_size, void* d_ws, size_t ws_size,
                              hipStream_t stream) {
    const float* x     = (const float*)d_in[0];
    const float* embed = (const float*)d_in[1];
    const float* W_in  = (const float*)d_in[2];
    const float* b_in  = (const float*)d_in[3];
    const float* W_out = (const float*)d_in[4];
    const float* b_out = (const float*)d_in[5];

    float* out_idx = (float*)d_out;              // [16384] indices as float
    float* out     = (float*)d_out + N_TOK;      // [16384,512]

    float* z   = (float*)d_ws;                   // [16384,256] = 16 MB
    float* esq = z + (size_t)N_TOK * CBD;        // [8192]
    int*   idx = (int*)(esq + CBS);              // [16384]

    // 1) z = x @ W_in^T + b_in
    gemm_nt<false><<<dim3(N_TOK / 64, CBD / 64), 256, 0, stream>>>(
        x, W_in, b_in, nullptr, z, N_TOK, CBD, DIM);
    // 2) ||e||^2
    esq_kernel<<<CBS / 4, 256, 0, stream>>>(embed, esq);
    // 3) nearest code per row
    score_argmax<<<N_TOK / 64, 256, 0, stream>>>(z, embed, esq, idx, out_idx);
    // 4) out = embed[idx] @ W_out^T + b_out
    gemm_nt<true><<<dim3(N_TOK / 64, DIM / 64), 256, 0, stream>>>(
        embed, W_out, b_out, idx, out, N_TOK, DIM, CBD);
}

// Round 2
// 563.417 us; speedup vs baseline: 2.9368x; 2.9368x over previous
//
#include <hip/hip_runtime.h>

#define N_TOK 16384   // B*T = 8*2048
#define DIM   512
#define CBD   256     // codebook dim
#define CBS   8192    // codebook size
#define KPACK 768     // 3*CBD for split-bf16 3-term product
#define KT    12      // KPACK/64
#define MARGIN 0.04f

typedef short short8 __attribute__((ext_vector_type(8)));
typedef float f32x4 __attribute__((ext_vector_type(4)));

#define GLOAD16(g, l) __builtin_amdgcn_global_load_lds( \
    (const __attribute__((address_space(1))) void*)(g), \
    (__attribute__((address_space(3))) void*)(l), 16, 0, 0)

__device__ inline unsigned short f2bf_rne(float f) {
    unsigned u = __float_as_uint(f);
    unsigned r = (u + 0x7FFFu + ((u >> 16) & 1u)) >> 16;
    return (unsigned short)r;
}
__device__ inline float bf2f(unsigned short h) { return __uint_as_float((unsigned)h << 16); }

// ---------------- e_sq: ||embed_c||^2 (exact f32) ----------------
__global__ __launch_bounds__(256) void esq_kernel(const float* __restrict__ embed,
                                                  float* __restrict__ esq) {
    int wave = threadIdx.x >> 6, lane = threadIdx.x & 63;
    int c = (blockIdx.x << 2) + wave;
    float4 v = reinterpret_cast<const float4*>(embed + (size_t)c * CBD)[lane];
    float s = v.x * v.x + v.y * v.y + v.z * v.z + v.w * v.w;
    #pragma unroll
    for (int m = 32; m; m >>= 1) s += __shfl_xor(s, m, 64);
    if (!lane) esq[c] = s;
}

// ---------------- generic f32 NT GEMM (used for project_in / project_out) ----------------
template <bool GATHER>
__global__ __launch_bounds__(256) void gemm_nt(const float* __restrict__ A,
                                               const float* __restrict__ B,
                                               const float* __restrict__ bias,
                                               const int* __restrict__ gather,
                                               float* __restrict__ C,
                                               int M, int N, int K) {
    __shared__ __align__(16) float sA[64][68];
    __shared__ __align__(16) float sB[64][68];
    const int tid = threadIdx.x;
    const int tx = tid & 15, ty = tid >> 4;
    const int bm = blockIdx.x << 6, bn = blockIdx.y << 6;
    float acc[4][4] = {};
    for (int k0 = 0; k0 < K; k0 += 64) {
        #pragma unroll
        for (int i = 0; i < 4; ++i) {
            int f = tid + (i << 8);
            int m = f >> 4;
            int k4 = (f & 15) << 2;
            long arow = bm + m;
            if (GATHER) arow = gather[arow];
            float4 v = *reinterpret_cast<const float4*>(A + arow * K + k0 + k4);
            sA[k4 + 0][m] = v.x; sA[k4 + 1][m] = v.y;
            sA[k4 + 2][m] = v.z; sA[k4 + 3][m] = v.w;
            float4 w = *reinterpret_cast<const float4*>(B + (long)(bn + m) * K + k0 + k4);
            sB[k4 + 0][m] = w.x; sB[k4 + 1][m] = w.y;
            sB[k4 + 2][m] = w.z; sB[k4 + 3][m] = w.w;
        }
        __syncthreads();
        #pragma unroll
        for (int kk = 0; kk < 64; ++kk) {
            float4 a = *reinterpret_cast<const float4*>(&sA[kk][ty << 2]);
            float4 b = *reinterpret_cast<const float4*>(&sB[kk][tx << 2]);
            float av[4] = {a.x, a.y, a.z, a.w};
            float bv[4] = {b.x, b.y, b.z, b.w};
            #pragma unroll
            for (int i = 0; i < 4; ++i)
                #pragma unroll
                for (int j = 0; j < 4; ++j)
                    acc[i][j] = fmaf(av[i], bv[j], acc[i][j]);
        }
        __syncthreads();
    }
    #pragma unroll
    for (int i = 0; i < 4; ++i) {
        long m = bm + (ty << 2) + i;
        #pragma unroll
        for (int j = 0; j < 4; ++j) {
            int n = bn + (tx << 2) + j;
            C[m * N + n] = acc[i][j] + bias[n];
        }
    }
}

// ---------------- packing: panel layout [tile128][kt][r128][k64] ----------------
__device__ inline size_t pk_off(int r, int kap) {
    return ((size_t)((r >> 7) * KT + (kap >> 6)) << 13) + (size_t)((r & 127) << 6) + (kap & 63);
}

// A = [z_hi | z_hi | z_lo]
__global__ __launch_bounds__(256) void pack_z(const float* __restrict__ z, short* __restrict__ Apack) {
    int e = blockIdx.x * 256 + threadIdx.x;       // < N_TOK*CBD
    int r = e >> 8, k = e & 255;
    float v = z[e];
    unsigned short zh = f2bf_rne(v);
    unsigned short zl = f2bf_rne(v - bf2f(zh));
    Apack[pk_off(r, k)]       = (short)zh;
    Apack[pk_off(r, k + 256)] = (short)zh;
    Apack[pk_off(r, k + 512)] = (short)zl;
}

// B = [e_hi | e_lo | e_hi]
__global__ __launch_bounds__(256) void pack_e(const float* __restrict__ embed, short* __restrict__ Bpack) {
    int e = blockIdx.x * 256 + threadIdx.x;       // < CBS*CBD
    int r = e >> 8, k = e & 255;
    float v = embed[e];
    unsigned short eh = f2bf_rne(v);
    unsigned short el = f2bf_rne(v - bf2f(eh));
    Bpack[pk_off(r, k)]       = (short)eh;
    Bpack[pk_off(r, k + 256)] = (short)el;
    Bpack[pk_off(r, k + 512)] = (short)eh;
}

// ---------------- stage A: bf16 MFMA score GEMM + per-row top-2 over 128-col tiles ----------------
// grid (M/128, N/128), 256 threads (4 waves, 2x2), BK=64, K=768.
__global__ __launch_bounds__(256) void score_mfma(const short* __restrict__ Apack,
                                                  const short* __restrict__ Bpack,
                                                  const float* __restrict__ esqg,
                                                  float4* __restrict__ partials) {
    __shared__ __align__(16) short sA[128 * 64];
    __shared__ __align__(16) short sB[128 * 64];
    __shared__ float4 sRed[4][64];
    const int tid = threadIdx.x;
    const int lane = tid & 63, wid = tid >> 6;
    const int wr = wid >> 1, wc = wid & 1;
    const int l15 = lane & 15, rg = lane >> 4;
    const int bm = blockIdx.x << 7, bn = blockIdx.y << 7;

    const char* aBase = (const char*)Apack + ((size_t)blockIdx.x * KT << 14);
    const char* bBase = (const char*)Bpack + ((size_t)blockIdx.y * KT << 14);
    char* sAc = (char*)sA;
    char* sBc = (char*)sB;

    f32x4 acc[4][4] = {};

    for (int kt = 0; kt < KT; ++kt) {
        const char* aP = aBase + ((size_t)kt << 14);
        const char* bP = bBase + ((size_t)kt << 14);
        #pragma unroll
        for (int i = 0; i < 4; ++i) {
            int off = ((wid * 4 + i) << 10) + (lane << 4);
            GLOAD16(aP + off, sAc + off);
            GLOAD16(bP + off, sBc + off);
        }
        __syncthreads();
        #pragma unroll
        for (int kk = 0; kk < 64; kk += 32) {
            short8 af[4], bf[4];
            #pragma unroll
            for (int mi = 0; mi < 4; ++mi)
                af[mi] = *(const short8*)&sA[(wr * 64 + mi * 16 + l15) * 64 + kk + rg * 8];
            #pragma unroll
            for (int ni = 0; ni < 4; ++ni)
                bf[ni] = *(const short8*)&sB[(wc * 64 + ni * 16 + l15) * 64 + kk + rg * 8];
            #pragma unroll
            for (int mi = 0; mi < 4; ++mi)
                #pragma unroll
                for (int ni = 0; ni < 4; ++ni)
                    acc[mi][ni] = __builtin_amdgcn_mfma_f32_16x16x32_bf16(af[mi], bf[ni], acc[mi][ni], 0, 0, 0);
        }
        __syncthreads();
    }

    // epilogue: per-row top-2 of s = 2*acc - e_sq within this block's 128 cols
    const int cbase = bn + wc * 64 + l15;
    float esq4[4];
    #pragma unroll
    for (int ni = 0; ni < 4; ++ni) esq4[ni] = esqg[cbase + ni * 16];

    #pragma unroll
    for (int mi = 0; mi < 4; ++mi) {
        #pragma unroll
        for (int j = 0; j < 4; ++j) {
            float v1 = -3.4e38f, v2 = -3.4e38f;
            int i1 = 0x7fffffff;
            #pragma unroll
            for (int ni = 0; ni < 4; ++ni) {
                float s = fmaf(2.0f, acc[mi][ni][j], -esq4[ni]);
                int c = cbase + ni * 16;
                if (s > v1 || (s == v1 && c < i1)) { v2 = v1; v1 = s; i1 = c; }
                else if (s >= v2) v2 = s;
            }
            #pragma unroll
            for (int m = 1; m < 16; m <<= 1) {
                float ov1 = __shfl_xor(v1, m, 64);
                int   oi1 = __shfl_xor(i1, m, 64);
                float ov2 = __shfl_xor(v2, m, 64);
                float nv2 = fmaxf(fmaxf(v2, ov2), fminf(v1, ov1));
                if (ov1 > v1 || (ov1 == v1 && oi1 < i1)) { v1 = ov1; i1 = oi1; }
                v2 = nv2;
            }
            if (l15 == 0) sRed[wid][mi * 16 + rg * 4 + j] = make_float4(v1, __int_as_float(i1), v2, 0.f);
        }
    }
    __syncthreads();
    if ((wid & 1) == 0) {
        float4 a = sRed[wid][lane], b = sRed[wid + 1][lane];
        float v1 = a.x; int i1 = __float_as_int(a.y); float v2a = a.z;
        float w1 = b.x; int j1 = __float_as_int(b.y); float v2b = b.z;
        float nv2 = fmaxf(fmaxf(v2a, v2b), fminf(v1, w1));
        if (w1 > v1 || (w1 == v1 && j1 < i1)) { v1 = w1; i1 = j1; }
        int grow = bm + (wid >> 1) * 64 + lane;
        partials[(size_t)grow * 64 + blockIdx.y] = make_float4(v1, __int_as_float(i1), nv2, 0.f);
    }
}

// ---------------- combine per-row partials, decide rescue ----------------
__global__ __launch_bounds__(256) void combine(const float4* __restrict__ partials,
                                               int* __restrict__ idx, float* __restrict__ idxf,
                                               float* __restrict__ rescueT) {
    int lane = threadIdx.x & 63;
    int row = blockIdx.x * 4 + (threadIdx.x >> 6);
    float4 p = partials[(size_t)row * 64 + lane];
    float v1 = p.x; int i1 = __float_as_int(p.y); float v2 = p.z;
    #pragma unroll
    for (int m = 1; m < 64; m <<= 1) {
        float ov1 = __shfl_xor(v1, m, 64);
        int   oi1 = __shfl_xor(i1, m, 64);
        float ov2 = __shfl_xor(v2, m, 64);
        float nv2 = fmaxf(fmaxf(v2, ov2), fminf(v1, ov1));
        if (ov1 > v1 || (ov1 == v1 && oi1 < i1)) { v1 = ov1; i1 = oi1; }
        v2 = nv2;
    }
    if (lane == 0) {
        idx[row] = i1;
        idxf[row] = (float)i1;
        rescueT[row] = (v1 - v2 <= MARGIN) ? (v1 - MARGIN) : 3.0e38f;
    }
}

// ---------------- exact f32 rescue for near-tie rows ----------------
__global__ __launch_bounds__(256) void rescue(const float* __restrict__ z,
                                              const float* __restrict__ embed,
                                              const float* __restrict__ esq,
                                              const float4* __restrict__ partials,
                                              const float* __restrict__ rescueT,
                                              int* __restrict__ idx, float* __restrict__ idxf) {
    int row = blockIdx.x;
    float t = rescueT[row];
    if (t > 1.0e38f) return;
    __shared__ float zrow[256];
    __shared__ float sv[256];
    __shared__ int   si[256];
    zrow[threadIdx.x] = z[(size_t)row * 256 + threadIdx.x];
    __syncthreads();
    float bv = -3.4e38f; int bi = 0x7fffffff;
    for (int nt = 0; nt < 64; ++nt) {
        if (partials[(size_t)row * 64 + nt].x < t) continue;  // block-uniform branch
        if (threadIdx.x < 128) {
            int c = nt * 128 + threadIdx.x;
            const float4* er = (const float4*)(embed + (size_t)c * 256);
            const float4* zr = (const float4*)zrow;
            float d = 0.f;
            #pragma unroll 4
            for (int k = 0; k < 64; ++k) {
                float4 e4 = er[k], z4 = zr[k];
                d = fmaf(e4.x, z4.x, d); d = fmaf(e4.y, z4.y, d);
                d = fmaf(e4.z, z4.z, d); d = fmaf(e4.w, z4.w, d);
            }
            float s = 2.f * d - esq[c];
            if (s > bv || (s == bv && c < bi)) { bv = s; bi = c; }
        }
    }
    sv[threadIdx.x] = bv; si[threadIdx.x] = bi;
    __syncthreads();
    for (int s = 128; s; s >>= 1) {
        if (threadIdx.x < s) {
            float ov = sv[threadIdx.x + s]; int oi = si[threadIdx.x + s];
            if (ov > sv[threadIdx.x] || (ov == sv[threadIdx.x] && oi < si[threadIdx.x])) {
                sv[threadIdx.x] = ov; si[threadIdx.x] = oi;
            }
        }
        __syncthreads();
    }
    if (threadIdx.x == 0) { idx[row] = si[0]; idxf[row] = (float)si[0]; }
}

// ---------------- fallback f32 score+argmax (baseline, used if ws too small) ----------------
__global__ __launch_bounds__(256) void score_argmax(const float* __restrict__ z,
                                                    const float* __restrict__ embed,
                                                    const float* __restrict__ esq,
                                                    int* __restrict__ idx_out,
                                                    float* __restrict__ idx_f32) {
    __shared__ __align__(16) float sZ[64][68];
    __shared__ __align__(16) float sE[64][68];
    const int tid = threadIdx.x;
    const int tx = tid & 15, ty = tid >> 4;
    const int bm = blockIdx.x << 6;
    float best[4];
    int bidx[4];
    #pragma unroll
    for (int i = 0; i < 4; ++i) { best[i] = -3.4e38f; bidx[i] = 0; }
    for (int ct = 0; ct < CBS; ct += 64) {
        float acc[4][4] = {};
        for (int k0 = 0; k0 < CBD; k0 += 64) {
            #pragma unroll
            for (int i = 0; i < 4; ++i) {
                int f = tid + (i << 8);
                int m = f >> 4;
                int k4 = (f & 15) << 2;
                float4 v = *reinterpret_cast<const float4*>(z + (long)(bm + m) * CBD + k0 + k4);
                sZ[k4 + 0][m] = v.x; sZ[k4 + 1][m] = v.y;
                sZ[k4 + 2][m] = v.z; sZ[k4 + 3][m] = v.w;
                float4 w = *reinterpret_cast<const float4*>(embed + (long)(ct + m) * CBD + k0 + k4);
                sE[k4 + 0][m] = w.x; sE[k4 + 1][m] = w.y;
                sE[k4 + 2][m] = w.z; sE[k4 + 3][m] = w.w;
            }
            __syncthreads();
            #pragma unroll
            for (int kk = 0; kk < 64; ++kk) {
                float4 a = *reinterpret_cast<const float4*>(&sZ[kk][ty << 2]);
                float4 b = *reinterpret_cast<const float4*>(&sE[kk][tx << 2]);
                float av[4] = {a.x, a.y, a.z, a.w};
                float bv[4] = {b.x, b.y, b.z, b.w};
                #pragma unroll
                for (int i = 0; i < 4; ++i)
                    #pragma unroll
                    for (int j = 0; j < 4; ++j)
                        acc[i][j] = fmaf(av[i], bv[j], acc[i][j]);
            }
            __syncthreads();
        }
        #pragma unroll
        for (int j = 0; j < 4; ++j) {
            int c = ct + (tx << 2) + j;
            float eq = esq[c];
            #pragma unroll
            for (int i = 0; i < 4; ++i) {
                float s = 2.0f * acc[i][j] - eq;
                if (s > best[i] || (s == best[i] && c < bidx[i])) { best[i] = s; bidx[i] = c; }
            }
        }
    }
    #pragma unroll
    for (int i = 0; i < 4; ++i) {
        float b = best[i];
        int bi = bidx[i];
        #pragma unroll
        for (int m = 1; m < 16; m <<= 1) {
            float ob = __shfl_xor(b, m, 64);
            int oi = __shfl_xor(bi, m, 64);
            if (ob > b || (ob == b && oi < bi)) { b = ob; bi = oi; }
        }
        if (tx == 0) {
            int row = bm + (ty << 2) + i;
            idx_out[row] = bi;
            idx_f32[row] = (float)bi;
        }
    }
}

extern "C" void kernel_launch(void* const* d_in, const int* in_sizes, int n_in,
                              void* d_out, int out_size, void* d_ws, size_t ws_size,
                              hipStream_t stream) {
    const float* x     = (const float*)d_in[0];
    const float* embed = (const float*)d_in[1];
    const float* W_in  = (const float*)d_in[2];
    const float* b_in  = (const float*)d_in[3];
    const float* W_out = (const float*)d_in[4];
    const float* b_out = (const float*)d_in[5];

    float* out_idx = (float*)d_out;              // [16384] indices as float
    float* out     = (float*)d_out + N_TOK;      // [16384,512]

    // workspace layout
    float* z       = (float*)d_ws;                         // 16384*256 f32
    float* esq     = z + (size_t)N_TOK * CBD;              // 8192
    float* rescueT = esq + CBS;                            // 16384
    int*   idx     = (int*)(rescueT + N_TOK);              // 16384
    float4* partials = (float4*)(idx + N_TOK);             // 16384*64 float4
    short* Apack   = (short*)(partials + (size_t)N_TOK * 64);  // 16384*768
    short* Bpack   = Apack + (size_t)N_TOK * KPACK;            // 8192*768
    size_t need = (size_t)((char*)(Bpack + (size_t)CBS * KPACK) - (char*)d_ws);

    // 1) z = x @ W_in^T + b_in   (exact f32)
    gemm_nt<false><<<dim3(N_TOK / 64, CBD / 64), 256, 0, stream>>>(
        x, W_in, b_in, nullptr, z, N_TOK, CBD, DIM);
    // 2) ||e||^2 exact
    esq_kernel<<<CBS / 4, 256, 0, stream>>>(embed, esq);

    if (ws_size < need) {
        // fallback: validated all-f32 path
        score_argmax<<<N_TOK / 64, 256, 0, stream>>>(z, embed, esq, idx, out_idx);
    } else {
        // 3) pack split-bf16 operands
        pack_z<<<N_TOK * CBD / 256, 256, 0, stream>>>(z, Apack);
        pack_e<<<CBS * CBD / 256, 256, 0, stream>>>(embed, Bpack);
        // 4) MFMA score GEMM + per-tile top-2
        score_mfma<<<dim3(N_TOK / 128, CBS / 128), 256, 0, stream>>>(Apack, Bpack, esq, partials);
        // 5) combine partials -> idx + rescue thresholds
        combine<<<N_TOK / 4, 256, 0, stream>>>(partials, idx, out_idx, rescueT);
        // 6) exact rescue for near-tie rows
        rescue<<<N_TOK, 256, 0, stream>>>(z, embed, esq, partials, rescueT, idx, out_idx);
    }
    // 7) out = embed[idx] @ W_out^T + b_out  (exact f32)
    gemm_nt<true><<<dim3(N_TOK / 64, DIM / 64), 256, 0, stream>>>(
        embed, W_out, b_out, idx, out, N_TOK, DIM, CBD);
}

// Round 3
// 558.048 us; speedup vs baseline: 2.9650x; 1.0096x over previous
//
#include <hip/hip_runtime.h>

#define N_TOK 16384   // B*T = 8*2048
#define DIM   512
#define CBD   256     // codebook dim
#define CBS   8192    // codebook size
#define KPACK 768     // 3*CBD for split-bf16 3-term product
#define KT3   24      // KPACK/32 (BK=32 K-tiles)
#define MARGIN 0.04f

typedef short short8 __attribute__((ext_vector_type(8)));
typedef float f32x4 __attribute__((ext_vector_type(4)));

#define GLOAD16(g, l) __builtin_amdgcn_global_load_lds( \
    (const __attribute__((address_space(1))) void*)(g), \
    (__attribute__((address_space(3))) void*)(l), 16, 0, 0)

// raw barrier with compiler memory fences (prevents ds_read hoisting across)
#define SBAR() do { asm volatile("" ::: "memory"); \
                    __builtin_amdgcn_s_barrier();  \
                    asm volatile("" ::: "memory"); } while (0)

__device__ inline unsigned short f2bf_rne(float f) {
    unsigned u = __float_as_uint(f);
    unsigned r = (u + 0x7FFFu + ((u >> 16) & 1u)) >> 16;
    return (unsigned short)r;
}
__device__ inline float bf2f(unsigned short h) { return __uint_as_float((unsigned)h << 16); }

// ---------------- e_sq: ||embed_c||^2 (exact f32) ----------------
__global__ __launch_bounds__(256) void esq_kernel(const float* __restrict__ embed,
                                                  float* __restrict__ esq) {
    int wave = threadIdx.x >> 6, lane = threadIdx.x & 63;
    int c = (blockIdx.x << 2) + wave;
    float4 v = reinterpret_cast<const float4*>(embed + (size_t)c * CBD)[lane];
    float s = v.x * v.x + v.y * v.y + v.z * v.z + v.w * v.w;
    #pragma unroll
    for (int m = 32; m; m >>= 1) s += __shfl_xor(s, m, 64);
    if (!lane) esq[c] = s;
}

// ---------------- generic f32 NT GEMM (project_in / project_out) ----------------
template <bool GATHER>
__global__ __launch_bounds__(256) void gemm_nt(const float* __restrict__ A,
                                               const float* __restrict__ B,
                                               const float* __restrict__ bias,
                                               const int* __restrict__ gather,
                                               float* __restrict__ C,
                                               int M, int N, int K) {
    __shared__ __align__(16) float sA[64][68];
    __shared__ __align__(16) float sB[64][68];
    const int tid = threadIdx.x;
    const int tx = tid & 15, ty = tid >> 4;
    const int bm = blockIdx.x << 6, bn = blockIdx.y << 6;
    float acc[4][4] = {};
    for (int k0 = 0; k0 < K; k0 += 64) {
        #pragma unroll
        for (int i = 0; i < 4; ++i) {
            int f = tid + (i << 8);
            int m = f >> 4;
            int k4 = (f & 15) << 2;
            long arow = bm + m;
            if (GATHER) arow = gather[arow];
            float4 v = *reinterpret_cast<const float4*>(A + arow * K + k0 + k4);
            sA[k4 + 0][m] = v.x; sA[k4 + 1][m] = v.y;
            sA[k4 + 2][m] = v.z; sA[k4 + 3][m] = v.w;
            float4 w = *reinterpret_cast<const float4*>(B + (long)(bn + m) * K + k0 + k4);
            sB[k4 + 0][m] = w.x; sB[k4 + 1][m] = w.y;
            sB[k4 + 2][m] = w.z; sB[k4 + 3][m] = w.w;
        }
        __syncthreads();
        #pragma unroll
        for (int kk = 0; kk < 64; ++kk) {
            float4 a = *reinterpret_cast<const float4*>(&sA[kk][ty << 2]);
            float4 b = *reinterpret_cast<const float4*>(&sB[kk][tx << 2]);
            float av[4] = {a.x, a.y, a.z, a.w};
            float bv[4] = {b.x, b.y, b.z, b.w};
            #pragma unroll
            for (int i = 0; i < 4; ++i)
                #pragma unroll
                for (int j = 0; j < 4; ++j)
                    acc[i][j] = fmaf(av[i], bv[j], acc[i][j]);
        }
        __syncthreads();
    }
    #pragma unroll
    for (int i = 0; i < 4; ++i) {
        long m = bm + (ty << 2) + i;
        #pragma unroll
        for (int j = 0; j < 4; ++j) {
            int n = bn + (tx << 2) + j;
            C[m * N + n] = acc[i][j] + bias[n];
        }
    }
}

// ---------------- packing ----------------
// Layout: [panel r>>8][kt 0..23][8192 shorts], within chunk: swizzled so that a
// LINEAR global_load_lds staging write produces the bank-conflict-free LDS image.
// LDS image (BK=32): short_idx = rp*32 + (kc ^ (((rp>>1)&3)<<3)); rows 2-way max.
__device__ inline size_t pk_off(int r, int kap) {
    int rp = r & 255, kt = kap >> 5, kc = kap & 31;
    return ((size_t)((r >> 8) * KT3 + kt) << 13) + (rp << 5) + (kc ^ (((rp >> 1) & 3) << 3));
}

// A = [z_hi | z_hi | z_lo]
__global__ __launch_bounds__(256) void pack_z(const float* __restrict__ z, short* __restrict__ Apack) {
    int e = blockIdx.x * 256 + threadIdx.x;       // < N_TOK*CBD
    int r = e >> 8, k = e & 255;
    float v = z[e];
    unsigned short zh = f2bf_rne(v);
    unsigned short zl = f2bf_rne(v - bf2f(zh));
    Apack[pk_off(r, k)]       = (short)zh;
    Apack[pk_off(r, k + 256)] = (short)zh;
    Apack[pk_off(r, k + 512)] = (short)zl;
}

// B = [e_hi | e_lo | e_hi]
__global__ __launch_bounds__(256) void pack_e(const float* __restrict__ embed, short* __restrict__ Bpack) {
    int e = blockIdx.x * 256 + threadIdx.x;       // < CBS*CBD
    int r = e >> 8, k = e & 255;
    float v = embed[e];
    unsigned short eh = f2bf_rne(v);
    unsigned short el = f2bf_rne(v - bf2f(eh));
    Bpack[pk_off(r, k)]       = (short)eh;
    Bpack[pk_off(r, k + 256)] = (short)el;
    Bpack[pk_off(r, k + 512)] = (short)eh;
}

// ---------------- 256x256 8-wave phase-pipelined score GEMM + per-tile top-2 ----
// grid (64,32) with bijective XCD swizzle, 512 threads (2Mx4N waves), BK=32,
// 3-slot LDS ring, counted vmcnt(4), setprio around 16-MFMA clusters.
__global__ __launch_bounds__(512, 2) void score_mfma(const short* __restrict__ Apack,
                                                     const short* __restrict__ Bpack,
                                                     const float* __restrict__ esqg,
                                                     float4* __restrict__ partials) {
    __shared__ __align__(16) char smem[98304];   // A: 3x16KB, B: 3x16KB
    const int tid = threadIdx.x;
    const int lane = tid & 63, wid = tid >> 6;
    const int wr = wid >> 2, wc = wid & 3;       // 2 x 4 waves
    const int l15 = lane & 15, rg = lane >> 4;

    int flat = blockIdx.y * 64 + blockIdx.x;
    int wg = ((flat & 7) << 8) | (flat >> 3);    // bijective (2048 % 8 == 0)
    int bX = wg & 63, bY = wg >> 6;
    const int bm = bX << 8, bn = bY << 8;

    char* ldsA0 = smem;
    char* ldsB0 = smem + 49152;
    const char* aPanel = (const char*)Apack + (size_t)bX * (KT3 * 16384);
    const char* bPanel = (const char*)Bpack + (size_t)bY * (KT3 * 16384);

    const int xr = (l15 >> 1) & 3;               // lane-constant swizzle XOR
    const int aOff = (wr * 128 + l15) * 64 + ((rg ^ xr) << 4);
    const int bOff = (wc * 64 + l15) * 64 + ((rg ^ xr) << 4);
    const int stgo = tid << 4;                   // 0..8191

    f32x4 acc[8][4] = {};

    // prologue: stage K-tiles 0 (slot0) and 1 (slot1)
    GLOAD16(aPanel + stgo,               ldsA0 + stgo);
    GLOAD16(aPanel + 8192 + stgo,        ldsA0 + 8192 + stgo);
    GLOAD16(bPanel + stgo,               ldsB0 + stgo);
    GLOAD16(bPanel + 8192 + stgo,        ldsB0 + 8192 + stgo);
    GLOAD16(aPanel + 16384 + stgo,        ldsA0 + 16384 + stgo);
    GLOAD16(aPanel + 16384 + 8192 + stgo, ldsA0 + 16384 + 8192 + stgo);
    GLOAD16(bPanel + 16384 + stgo,        ldsB0 + 16384 + stgo);
    GLOAD16(bPanel + 16384 + 8192 + stgo, ldsB0 + 16384 + 8192 + stgo);
    asm volatile("s_waitcnt vmcnt(4)" ::: "memory");   // tile 0 landed
    SBAR();

    int slot = 0;
    #pragma unroll 1
    for (int t = 0; t < KT3; ++t) {
        const char* lA = ldsA0 + slot * 16384;
        const char* lB = ldsB0 + slot * 16384;
        int slot2 = slot + 2; if (slot2 >= 3) slot2 -= 3;
        char* dA = ldsA0 + slot2 * 16384;
        char* dB = ldsB0 + slot2 * 16384;
        const char* sA2 = aPanel + (size_t)(t + 2) * 16384;
        const char* sB2 = bPanel + (size_t)(t + 2) * 16384;
        const bool stg = (t + 2 < KT3);

        // ---- phase 0: read A mi0-3 + B ni0-3, stage first halves, 16 MFMA ----
        short8 aF[4], bF[4];
        #pragma unroll
        for (int mi = 0; mi < 4; ++mi) aF[mi] = *(const short8*)(lA + aOff + mi * 1024);
        #pragma unroll
        for (int ni = 0; ni < 4; ++ni) bF[ni] = *(const short8*)(lB + bOff + ni * 1024);
        if (stg) { GLOAD16(sA2 + stgo, dA + stgo); GLOAD16(sB2 + stgo, dB + stgo); }
        SBAR();
        __builtin_amdgcn_s_setprio(1);
        #pragma unroll
        for (int mi = 0; mi < 4; ++mi)
            #pragma unroll
            for (int ni = 0; ni < 4; ++ni)
                acc[mi][ni] = __builtin_amdgcn_mfma_f32_16x16x32_bf16(aF[mi], bF[ni], acc[mi][ni], 0, 0, 0);
        __builtin_amdgcn_s_setprio(0);
        SBAR();

        // ---- phase 1: read A mi4-7 (reuse B), stage second halves, 16 MFMA ----
        short8 aG[4];
        #pragma unroll
        for (int mi = 0; mi < 4; ++mi) aG[mi] = *(const short8*)(lA + aOff + (mi + 4) * 1024);
        if (stg) { GLOAD16(sA2 + 8192 + stgo, dA + 8192 + stgo);
                   GLOAD16(sB2 + 8192 + stgo, dB + 8192 + stgo); }
        SBAR();
        __builtin_amdgcn_s_setprio(1);
        #pragma unroll
        for (int mi = 0; mi < 4; ++mi)
            #pragma unroll
            for (int ni = 0; ni < 4; ++ni)
                acc[mi + 4][ni] = __builtin_amdgcn_mfma_f32_16x16x32_bf16(aG[mi], bF[ni], acc[mi + 4][ni], 0, 0, 0);
        __builtin_amdgcn_s_setprio(0);
        // counted vmcnt: keep tile t+2's 4 loads in flight, require t+1 landed
        if (t < KT3 - 2) { asm volatile("s_waitcnt vmcnt(4)" ::: "memory"); }
        else             { asm volatile("s_waitcnt vmcnt(0)" ::: "memory"); }
        SBAR();

        slot = slot + 1; if (slot >= 3) slot = 0;
    }

    // ---- epilogue: per-row top-2 of s = 2*acc - e_sq over this block's 256 cols
    float4* sRed = (float4*)smem;                // reuse ring LDS (all reads done)
    const int cbase = bn + wc * 64 + l15;
    float esq4[4];
    #pragma unroll
    for (int ni = 0; ni < 4; ++ni) esq4[ni] = esqg[cbase + ni * 16];

    #pragma unroll
    for (int mi = 0; mi < 8; ++mi) {
        #pragma unroll
        for (int j = 0; j < 4; ++j) {
            float v1 = -3.4e38f, v2 = -3.4e38f;
            int i1 = 0x7fffffff;
            #pragma unroll
            for (int ni = 0; ni < 4; ++ni) {
                float s = fmaf(2.0f, acc[mi][ni][j], -esq4[ni]);
                int c = cbase + ni * 16;
                if (s > v1) { v2 = v1; v1 = s; i1 = c; }
                else if (s > v2) v2 = s;
            }
            #pragma unroll
            for (int m = 1; m < 16; m <<= 1) {
                float ov1 = __shfl_xor(v1, m, 64);
                int   oi1 = __shfl_xor(i1, m, 64);
                float ov2 = __shfl_xor(v2, m, 64);
                float nv2 = fmaxf(fmaxf(v2, ov2), fminf(v1, ov1));
                if (ov1 > v1 || (ov1 == v1 && oi1 < i1)) { v1 = ov1; i1 = oi1; }
                v2 = nv2;
            }
            if (l15 == 0) sRed[wid * 128 + mi * 16 + rg * 4 + j] =
                make_float4(v1, __int_as_float(i1), v2, 0.f);
        }
    }
    __syncthreads();
    if (wc < 2) {
        int row = (wc << 6) + lane;              // 0..127 within band
        float4 e0 = sRed[(wr * 4 + 0) * 128 + row];
        float4 e1 = sRed[(wr * 4 + 1) * 128 + row];
        float4 e2 = sRed[(wr * 4 + 2) * 128 + row];
        float4 e3 = sRed[(wr * 4 + 3) * 128 + row];
        float v1 = e0.x; int i1 = __float_as_int(e0.y); float v2 = e0.z;
        {   float w1 = e1.x; int jx = __float_as_int(e1.y);
            float nv2 = fmaxf(fmaxf(v2, e1.z), fminf(v1, w1));
            if (w1 > v1 || (w1 == v1 && jx < i1)) { v1 = w1; i1 = jx; }
            v2 = nv2; }
        {   float w1 = e2.x; int jx = __float_as_int(e2.y);
            float nv2 = fmaxf(fmaxf(v2, e2.z), fminf(v1, w1));
            if (w1 > v1 || (w1 == v1 && jx < i1)) { v1 = w1; i1 = jx; }
            v2 = nv2; }
        {   float w1 = e3.x; int jx = __float_as_int(e3.y);
            float nv2 = fmaxf(fmaxf(v2, e3.z), fminf(v1, w1));
            if (w1 > v1 || (w1 == v1 && jx < i1)) { v1 = w1; i1 = jx; }
            v2 = nv2; }
        int grow = bm + (wr << 7) + row;
        partials[(size_t)grow * 32 + bY] = make_float4(v1, __int_as_float(i1), v2, 0.f);
    }
}

// ---------------- combine per-row partials (32 tiles), decide rescue ----------------
__global__ __launch_bounds__(256) void combine(const float4* __restrict__ partials,
                                               int* __restrict__ idx, float* __restrict__ idxf,
                                               float* __restrict__ rescueT) {
    int sub = threadIdx.x & 31;
    int row = blockIdx.x * 8 + (threadIdx.x >> 5);
    float4 p = partials[(size_t)row * 32 + sub];
    float v1 = p.x; int i1 = __float_as_int(p.y); float v2 = p.z;
    #pragma unroll
    for (int m = 1; m < 32; m <<= 1) {
        float ov1 = __shfl_xor(v1, m, 64);
        int   oi1 = __shfl_xor(i1, m, 64);
        float ov2 = __shfl_xor(v2, m, 64);
        float nv2 = fmaxf(fmaxf(v2, ov2), fminf(v1, ov1));
        if (ov1 > v1 || (ov1 == v1 && oi1 < i1)) { v1 = ov1; i1 = oi1; }
        v2 = nv2;
    }
    if (sub == 0) {
        idx[row] = i1;
        idxf[row] = (float)i1;
        rescueT[row] = (v1 - v2 <= MARGIN) ? (v1 - MARGIN) : 3.0e38f;
    }
}

// ---------------- exact f32 rescue for near-tie rows ----------------
__global__ __launch_bounds__(256) void rescue(const float* __restrict__ z,
                                              const float* __restrict__ embed,
                                              const float* __restrict__ esq,
                                              const float4* __restrict__ partials,
                                              const float* __restrict__ rescueT,
                                              int* __restrict__ idx, float* __restrict__ idxf) {
    int row = blockIdx.x;
    float t = rescueT[row];
    if (t > 1.0e38f) return;
    __shared__ float zrow[256];
    __shared__ float sv[256];
    __shared__ int   si[256];
    zrow[threadIdx.x] = z[(size_t)row * 256 + threadIdx.x];
    __syncthreads();
    float bv = -3.4e38f; int bi = 0x7fffffff;
    for (int nt = 0; nt < 32; ++nt) {
        if (partials[(size_t)row * 32 + nt].x < t) continue;  // block-uniform
        int c = nt * 256 + threadIdx.x;
        const float4* er = (const float4*)(embed + (size_t)c * 256);
        const float4* zr = (const float4*)zrow;
        float d = 0.f;
        #pragma unroll 4
        for (int k = 0; k < 64; ++k) {
            float4 e4 = er[k], z4 = zr[k];
            d = fmaf(e4.x, z4.x, d); d = fmaf(e4.y, z4.y, d);
            d = fmaf(e4.z, z4.z, d); d = fmaf(e4.w, z4.w, d);
        }
        float s = 2.f * d - esq[c];
        if (s > bv || (s == bv && c < bi)) { bv = s; bi = c; }
    }
    sv[threadIdx.x] = bv; si[threadIdx.x] = bi;
    __syncthreads();
    for (int s = 128; s; s >>= 1) {
        if (threadIdx.x < s) {
            float ov = sv[threadIdx.x + s]; int oi = si[threadIdx.x + s];
            if (ov > sv[threadIdx.x] || (ov == sv[threadIdx.x] && oi < si[threadIdx.x])) {
                sv[threadIdx.x] = ov; si[threadIdx.x] = oi;
            }
        }
        __syncthreads();
    }
    if (threadIdx.x == 0) { idx[row] = si[0]; idxf[row] = (float)si[0]; }
}

// ---------------- fallback f32 score+argmax (ws too small) ----------------
__global__ __launch_bounds__(256) void score_argmax(const float* __restrict__ z,
                                                    const float* __restrict__ embed,
                                                    const float* __restrict__ esq,
                                                    int* __restrict__ idx_out,
                                                    float* __restrict__ idx_f32) {
    __shared__ __align__(16) float sZ[64][68];
    __shared__ __align__(16) float sE[64][68];
    const int tid = threadIdx.x;
    const int tx = tid & 15, ty = tid >> 4;
    const int bm = blockIdx.x << 6;
    float best[4];
    int bidx[4];
    #pragma unroll
    for (int i = 0; i < 4; ++i) { best[i] = -3.4e38f; bidx[i] = 0; }
    for (int ct = 0; ct < CBS; ct += 64) {
        float acc[4][4] = {};
        for (int k0 = 0; k0 < CBD; k0 += 64) {
            #pragma unroll
            for (int i = 0; i < 4; ++i) {
                int f = tid + (i << 8);
                int m = f >> 4;
                int k4 = (f & 15) << 2;
                float4 v = *reinterpret_cast<const float4*>(z + (long)(bm + m) * CBD + k0 + k4);
                sZ[k4 + 0][m] = v.x; sZ[k4 + 1][m] = v.y;
                sZ[k4 + 2][m] = v.z; sZ[k4 + 3][m] = v.w;
                float4 w = *reinterpret_cast<const float4*>(embed + (long)(ct + m) * CBD + k0 + k4);
                sE[k4 + 0][m] = w.x; sE[k4 + 1][m] = w.y;
                sE[k4 + 2][m] = w.z; sE[k4 + 3][m] = w.w;
            }
            __syncthreads();
            #pragma unroll
            for (int kk = 0; kk < 64; ++kk) {
                float4 a = *reinterpret_cast<const float4*>(&sZ[kk][ty << 2]);
                float4 b = *reinterpret_cast<const float4*>(&sE[kk][tx << 2]);
                float av[4] = {a.x, a.y, a.z, a.w};
                float bv[4] = {b.x, b.y, b.z, b.w};
                #pragma unroll
                for (int i = 0; i < 4; ++i)
                    #pragma unroll
                    for (int j = 0; j < 4; ++j)
                        acc[i][j] = fmaf(av[i], bv[j], acc[i][j]);
            }
            __syncthreads();
        }
        #pragma unroll
        for (int j = 0; j < 4; ++j) {
            int c = ct + (tx << 2) + j;
            float eq = esq[c];
            #pragma unroll
            for (int i = 0; i < 4; ++i) {
                float s = 2.0f * acc[i][j] - eq;
                if (s > best[i] || (s == best[i] && c < bidx[i])) { best[i] = s; bidx[i] = c; }
            }
        }
    }
    #pragma unroll
    for (int i = 0; i < 4; ++i) {
        float b = best[i];
        int bi = bidx[i];
        #pragma unroll
        for (int m = 1; m < 16; m <<= 1) {
            float ob = __shfl_xor(b, m, 64);
            int oi = __shfl_xor(bi, m, 64);
            if (ob > b || (ob == b && oi < bi)) { b = ob; bi = oi; }
        }
        if (tx == 0) {
            int row = bm + (ty << 2) + i;
            idx_out[row] = bi;
            idx_f32[row] = (float)bi;
        }
    }
}

extern "C" void kernel_launch(void* const* d_in, const int* in_sizes, int n_in,
                              void* d_out, int out_size, void* d_ws, size_t ws_size,
                              hipStream_t stream) {
    const float* x     = (const float*)d_in[0];
    const float* embed = (const float*)d_in[1];
    const float* W_in  = (const float*)d_in[2];
    const float* b_in  = (const float*)d_in[3];
    const float* W_out = (const float*)d_in[4];
    const float* b_out = (const float*)d_in[5];

    float* out_idx = (float*)d_out;              // [16384] indices as float
    float* out     = (float*)d_out + N_TOK;      // [16384,512]

    // workspace layout
    float* z       = (float*)d_ws;                         // 16384*256 f32
    float* esq     = z + (size_t)N_TOK * CBD;              // 8192
    float* rescueT = esq + CBS;                            // 16384
    int*   idx     = (int*)(rescueT + N_TOK);              // 16384
    float4* partials = (float4*)(idx + N_TOK);             // 16384*32 float4
    short* Apack   = (short*)(partials + (size_t)N_TOK * 32);  // 16384*768
    short* Bpack   = Apack + (size_t)N_TOK * KPACK;            // 8192*768
    size_t need = (size_t)((char*)(Bpack + (size_t)CBS * KPACK) - (char*)d_ws);

    // 1) z = x @ W_in^T + b_in   (exact f32)
    gemm_nt<false><<<dim3(N_TOK / 64, CBD / 64), 256, 0, stream>>>(
        x, W_in, b_in, nullptr, z, N_TOK, CBD, DIM);
    // 2) ||e||^2 exact
    esq_kernel<<<CBS / 4, 256, 0, stream>>>(embed, esq);

    if (ws_size < need) {
        score_argmax<<<N_TOK / 64, 256, 0, stream>>>(z, embed, esq, idx, out_idx);
    } else {
        // 3) pack split-bf16 operands (swizzle baked into layout)
        pack_z<<<N_TOK * CBD / 256, 256, 0, stream>>>(z, Apack);
        pack_e<<<CBS * CBD / 256, 256, 0, stream>>>(embed, Bpack);
        // 4) 256x256 phase-pipelined MFMA score GEMM + per-tile top-2
        score_mfma<<<dim3(64, 32), 512, 0, stream>>>(Apack, Bpack, esq, partials);
        // 5) combine partials -> idx + rescue thresholds
        combine<<<N_TOK / 8, 256, 0, stream>>>(partials, idx, out_idx, rescueT);
        // 6) exact rescue for near-tie rows
        rescue<<<N_TOK, 256, 0, stream>>>(z, embed, esq, partials, rescueT, idx, out_idx);
    }
    // 7) out = embed[idx] @ W_out^T + b_out  (exact f32)
    gemm_nt<true><<<dim3(N_TOK / 64, DIM / 64), 256, 0, stream>>>(
        embed, W_out, b_out, idx, out, N_TOK, DIM, CBD);
}

// Round 5
// 511.985 us; speedup vs baseline: 3.2318x; 1.0900x over previous
//
#include <hip/hip_runtime.h>

#define N_TOK 16384   // B*T = 8*2048
#define DIM   512
#define CBD   256     // codebook dim
#define CBS   8192    // codebook size
#define MARGIN 0.08f

typedef short short8 __attribute__((ext_vector_type(8)));
typedef float f32x4 __attribute__((ext_vector_type(4)));

#define GLOAD16(g, l) __builtin_amdgcn_global_load_lds( \
    (const __attribute__((address_space(1))) void*)(g), \
    (__attribute__((address_space(3))) void*)(l), 16, 0, 0)

#define SBAR() do { asm volatile("" ::: "memory"); \
                    __builtin_amdgcn_s_barrier();  \
                    asm volatile("" ::: "memory"); } while (0)
#define LGKM0() do { asm volatile("s_waitcnt lgkmcnt(0)" ::: "memory"); \
                     __builtin_amdgcn_sched_barrier(0); } while (0)
#define VMCNT(n) asm volatile("s_waitcnt vmcnt(" #n ")" ::: "memory")
#define PRIO1() __builtin_amdgcn_s_setprio(1)
#define PRIO0() __builtin_amdgcn_s_setprio(0)

__device__ inline unsigned short f2bf_rne(float f) {
    unsigned u = __float_as_uint(f);
    unsigned r = (u + 0x7FFFu + ((u >> 16) & 1u)) >> 16;
    return (unsigned short)r;
}
__device__ inline float bf2f(unsigned short h) { return __uint_as_float((unsigned)h << 16); }

// ================= packing: 2-term split [hi(K) | lo(K)] per row ==============
template <int LOGK>
__global__ __launch_bounds__(256) void pack_w(const float* __restrict__ src, short* __restrict__ dst) {
    int e = blockIdx.x * 256 + threadIdx.x;
    int r = e >> LOGK, k = e & ((1 << LOGK) - 1);
    float v = src[e];
    unsigned short h = f2bf_rne(v);
    unsigned short l = f2bf_rne(v - bf2f(h));
    size_t base = (size_t)r << (LOGK + 1);
    dst[base + k] = (short)h;
    dst[base + (1 << LOGK) + k] = (short)l;
}

// fused: e_sq (exact f32) + 2-term embed pack
__global__ __launch_bounds__(256) void prep_embed(const float* __restrict__ embed,
                                                  float* __restrict__ esq,
                                                  short* __restrict__ epack) {
    int wave = threadIdx.x >> 6, lane = threadIdx.x & 63;
    int c = (blockIdx.x << 2) + wave;
    float4 v = reinterpret_cast<const float4*>(embed + (size_t)c * CBD)[lane];
    short4 hs, ls;
    {
        unsigned short h, l;
        h = f2bf_rne(v.x); l = f2bf_rne(v.x - bf2f(h)); hs.x = h; ls.x = l;
        h = f2bf_rne(v.y); l = f2bf_rne(v.y - bf2f(h)); hs.y = h; ls.y = l;
        h = f2bf_rne(v.z); l = f2bf_rne(v.z - bf2f(h)); hs.z = h; ls.z = l;
        h = f2bf_rne(v.w); l = f2bf_rne(v.w - bf2f(h)); hs.w = h; ls.w = l;
    }
    reinterpret_cast<short4*>(epack + (size_t)c * 512)[lane] = hs;
    reinterpret_cast<short4*>(epack + (size_t)c * 512 + 256)[lane] = ls;
    float s = v.x * v.x + v.y * v.y + v.z * v.z + v.w * v.w;
    #pragma unroll
    for (int m = 32; m; m >>= 1) s += __shfl_xor(s, m, 64);
    if (!lane) esq[c] = s;
}

// ============ gemm_in: z = x@W_in^T + b_in, 4-term split-bf16, BM=64 BN=128 ===
// K2=2048 (32 kt). A chunk order: [xh|xh|xl|xl]; B: [wh|wl|wh|wl].
// Writes 2-term packed z directly ([token][zh 256 | zl 256]).
__global__ __launch_bounds__(256, 3) void gemm_in_mfma(const short* __restrict__ xpk,
                                                       const short* __restrict__ wpk,
                                                       const float* __restrict__ b_in,
                                                       short* __restrict__ zpack) {
    __shared__ __align__(16) char smem[49152];   // per buf: A 8KB + B 16KB, 2 bufs
    const int tid = threadIdx.x;
    const int lane = tid & 63, wid = tid >> 6;
    const int l15 = lane & 15, rg = lane >> 4;
    const int bm = blockIdx.x << 6, bn = blockIdx.y << 7;
    const int g = tid & 7, rpb = tid >> 3;       // rpb 0..31

    const char* xb = (const char*)xpk;
    const char* wb = (const char*)wpk;
    const int sw = ((g ^ (rpb & 7)) << 4);
    // packed rows are 1024 shorts = 2048 BYTES (this stride was the round-4 bug)
    size_t aoff[2], boff[2][2];
    #pragma unroll
    for (int it = 0; it < 2; ++it)
        aoff[it] = (size_t)(bm + it * 32 + rpb) * 2048 + sw;
    #pragma unroll
    for (int it = 0; it < 4; ++it)
        boff[it >> 1][it & 1] = (size_t)(bn + it * 32 + rpb) * 2048 + sw;

    const int ax0 = ((rg ^ (l15 & 7)) << 4);
    const int ax1 = (((rg + 4) ^ (l15 & 7)) << 4);
    const char* aBase = smem + l15 * 128;
    const char* bBase = smem + 8192 + (wid * 32 + l15) * 128;

    f32x4 acc[4][2] = {};

#define GIN_STAGE(BUF, KT) do { \
    size_t aK = (size_t)(((((KT) >> 4) << 3) | ((KT) & 7))) * 128; \
    size_t bK = (size_t)((((((KT) >> 3) & 1) << 3) | ((KT) & 7))) * 128; \
    char* dA = smem + (BUF) * 24576 + (tid << 4); \
    char* dB = dA + 8192; \
    GLOAD16(xb + aoff[0] + aK, dA); \
    GLOAD16(xb + aoff[1] + aK, dA + 4096); \
    GLOAD16(wb + boff[0][0] + bK, dB); \
    GLOAD16(wb + boff[0][1] + bK, dB + 4096); \
    GLOAD16(wb + boff[1][0] + bK, dB + 8192); \
    GLOAD16(wb + boff[1][1] + bK, dB + 12288); } while (0)

    GIN_STAGE(0, 0);
    VMCNT(0);
    __syncthreads();
    #pragma unroll 1
    for (int kt = 0; kt < 32; ++kt) {
        const int buf = kt & 1;
        if (kt + 1 < 32) GIN_STAGE(buf ^ 1, kt + 1);
        const char* aB = aBase + buf * 24576;
        const char* bB = bBase + buf * 24576;
        #pragma unroll
        for (int ks = 0; ks < 2; ++ks) {
            int ax = ks ? ax1 : ax0;
            short8 aF[4], bF[2];
            #pragma unroll
            for (int mi = 0; mi < 4; ++mi) aF[mi] = *(const short8*)(aB + mi * 2048 + ax);
            #pragma unroll
            for (int ni = 0; ni < 2; ++ni) bF[ni] = *(const short8*)(bB + ni * 2048 + ax);
            #pragma unroll
            for (int mi = 0; mi < 4; ++mi)
                #pragma unroll
                for (int ni = 0; ni < 2; ++ni)
                    acc[mi][ni] = __builtin_amdgcn_mfma_f32_16x16x32_bf16(aF[mi], bF[ni], acc[mi][ni], 0, 0, 0);
        }
        VMCNT(0);
        __syncthreads();
    }
    // epilogue: add bias, 2-term split, write zpack[token][zh 0..255 | zl 256..511]
    float bb[2];
    #pragma unroll
    for (int ni = 0; ni < 2; ++ni) bb[ni] = b_in[bn + wid * 32 + ni * 16 + l15];
    #pragma unroll
    for (int mi = 0; mi < 4; ++mi)
        #pragma unroll
        for (int ni = 0; ni < 2; ++ni)
            #pragma unroll
            for (int j = 0; j < 4; ++j) {
                int r = bm + mi * 16 + rg * 4 + j;
                int c = bn + wid * 32 + ni * 16 + l15;
                float s = acc[mi][ni][j] + bb[ni];
                unsigned short zh = f2bf_rne(s);
                unsigned short zl = f2bf_rne(s - bf2f(zh));
                zpack[(size_t)r * 512 + c] = (short)zh;
                zpack[(size_t)r * 512 + 256 + c] = (short)zl;
            }
}

// ===== score: 256x256 8-phase (m201-style), K=768 (12 kt of 64), top-2 epilogue
// A chunks (zpack, 8/row): kt->((kt>>3)<<2)|(kt&3)  [zh,zh,zl]
// B chunks (epack, 8/row): kt->kt&7                 [eh,el,eh]
__global__ __launch_bounds__(512, 2) void score_mfma(const short* __restrict__ zpk,
                                                     const short* __restrict__ epk,
                                                     const float* __restrict__ esqg,
                                                     float4* __restrict__ partials) {
    __shared__ __align__(16) char smem[131072];  // A: 2buf x 2half x 16KB; B same at +65536
    const int tid = threadIdx.x;
    const int lane = tid & 63, wid = tid >> 6;
    const int wr = wid >> 2, wc = wid & 3;
    const int l15 = lane & 15, rg = lane >> 4;

    // XCD band mapping: each XCD owns 8 consecutive bX (3MB A band resident in L2)
    int flat = blockIdx.x;
    int xcd = flat & 7, ix = flat >> 3;
    int bX = xcd * 8 + (ix & 7), bY = ix >> 3;
    const int bm = bX << 8, bn = bY << 8;
    const size_t bmB = (size_t)bX << 18;         // *256*1024
    const size_t bnB = (size_t)bY << 18;

    const char* zb = (const char*)zpk;
    const char* eb = (const char*)epk;
    const int g = tid & 7, rp0 = tid >> 3;       // rp0 0..63
    const size_t arow = (size_t)rp0 * 1024 + ((g ^ (rp0 & 7)) << 4);

#define SC_STAGE_A(BUF, H, KT) do { \
    const char* s_ = zb + bmB + (size_t)(H) * 131072 + (size_t)((((KT) >> 3) << 2) | ((KT) & 3)) * 128 + arow; \
    char* d_ = smem + (BUF) * 32768 + (H) * 16384 + (tid << 4); \
    GLOAD16(s_, d_); GLOAD16(s_ + 65536, d_ + 8192); } while (0)
#define SC_STAGE_B(BUF, H, KT) do { \
    const char* s_ = eb + bnB + (size_t)(H) * 131072 + (size_t)((KT) & 7) * 128 + arow; \
    char* d_ = smem + 65536 + (BUF) * 32768 + (H) * 16384 + (tid << 4); \
    GLOAD16(s_, d_); GLOAD16(s_ + 65536, d_ + 8192); } while (0)

    const int ax0 = ((rg ^ (l15 & 7)) << 4);
    const int ax1 = (((rg + 4) ^ (l15 & 7)) << 4);
    const char* aBase = smem + wr * 16384 + l15 * 128;
    const char* bBase = smem + 65536 + (wc >> 1) * 16384 + ((wc & 1) * 64 + l15) * 128;

#define RD_A4(DST, BUF, MIB, AXR) { _Pragma("unroll") for (int mi_ = 0; mi_ < 4; ++mi_) \
    DST[mi_] = *(const short8*)(aBase + (BUF) * 32768 + ((MIB) + mi_) * 2048 + (AXR)); }
#define RD_B4(DST, BUF, AXR) { _Pragma("unroll") for (int ni_ = 0; ni_ < 4; ++ni_) \
    DST[ni_] = *(const short8*)(bBase + (BUF) * 32768 + ni_ * 2048 + (AXR)); }
#define MM16(R0, AF, BF) { _Pragma("unroll") for (int mi_ = 0; mi_ < 4; ++mi_) { \
    _Pragma("unroll") for (int ni_ = 0; ni_ < 4; ++ni_) \
      acc[(R0) + mi_][ni_] = __builtin_amdgcn_mfma_f32_16x16x32_bf16(AF[mi_], BF[ni_], acc[(R0) + mi_][ni_], 0, 0, 0); } }

    f32x4 acc[8][4] = {};

    // prologue: tile0 -> buf0 (all 4 halves), tile1.Bh0 -> buf1
    SC_STAGE_B(0, 0, 0); SC_STAGE_B(0, 1, 0);
    SC_STAGE_A(0, 0, 0); SC_STAGE_A(0, 1, 0);
    SC_STAGE_B(1, 0, 1);
    VMCNT(2);
    SBAR();

    #pragma unroll 1
    for (int i = 0; i < 6; ++i) {
        const int t1 = 2 * i + 1;
        const bool st = (i < 5);
        short8 aF[4], aG[4], bF0[4], bF1[4];
        // ph1: buf0 A(0-3,ks0)+B(ks0); stage buf1.Bh1<-t1
        RD_A4(aF, 0, 0, ax0); RD_B4(bF0, 0, ax0);
        SC_STAGE_B(1, 1, t1);
        SBAR(); LGKM0(); PRIO1(); MM16(0, aF, bF0); PRIO0(); SBAR();
        // ph2: A(4-7,ks0); stage buf1.Ah0<-t1
        RD_A4(aG, 0, 4, ax0);
        SC_STAGE_A(1, 0, t1);
        SBAR(); LGKM0(); PRIO1(); MM16(4, aG, bF0); PRIO0(); SBAR();
        // ph3: A(0-3,ks1)+B(ks1); stage buf1.Ah1<-t1
        RD_A4(aF, 0, 0, ax1); RD_B4(bF1, 0, ax1);
        SC_STAGE_A(1, 1, t1);
        SBAR(); LGKM0(); PRIO1(); MM16(0, aF, bF1); PRIO0(); SBAR();
        // ph4: A(4-7,ks1); stage buf0.Bh0<-t0+2; vmcnt
        RD_A4(aG, 0, 4, ax1);
        if (st) SC_STAGE_B(0, 0, 2 * i + 2);
        SBAR(); LGKM0(); PRIO1(); MM16(4, aG, bF1); PRIO0();
        if (st) { VMCNT(2); } else { VMCNT(0); }
        SBAR();
        // ph5: buf1 A(0-3,ks0)+B(ks0); stage buf0.Bh1
        RD_A4(aF, 1, 0, ax0); RD_B4(bF0, 1, ax0);
        if (st) SC_STAGE_B(0, 1, 2 * i + 2);
        SBAR(); LGKM0(); PRIO1(); MM16(0, aF, bF0); PRIO0(); SBAR();
        // ph6
        RD_A4(aG, 1, 4, ax0);
        if (st) SC_STAGE_A(0, 0, 2 * i + 2);
        SBAR(); LGKM0(); PRIO1(); MM16(4, aG, bF0); PRIO0(); SBAR();
        // ph7
        RD_A4(aF, 1, 0, ax1); RD_B4(bF1, 1, ax1);
        if (st) SC_STAGE_A(0, 1, 2 * i + 2);
        SBAR(); LGKM0(); PRIO1(); MM16(0, aF, bF1); PRIO0(); SBAR();
        // ph8: stage buf1.Bh0<-t1+2; vmcnt
        RD_A4(aG, 1, 4, ax1);
        if (st) SC_STAGE_B(1, 0, 2 * i + 3);
        SBAR(); LGKM0(); PRIO1(); MM16(4, aG, bF1); PRIO0();
        if (st) { VMCNT(2); } else { VMCNT(0); }
        SBAR();
    }

    // epilogue: per-row top-2 of s = 2*acc - e_sq over this block's 256 cols
    float4* sRed = (float4*)smem;
    const int cbase = bn + wc * 64 + l15;
    float esq4[4];
    #pragma unroll
    for (int ni = 0; ni < 4; ++ni) esq4[ni] = esqg[cbase + ni * 16];

    #pragma unroll
    for (int mi = 0; mi < 8; ++mi) {
        #pragma unroll
        for (int j = 0; j < 4; ++j) {
            float v1 = -3.4e38f, v2 = -3.4e38f;
            int i1 = 0x7fffffff;
            #pragma unroll
            for (int ni = 0; ni < 4; ++ni) {
                float s = fmaf(2.0f, acc[mi][ni][j], -esq4[ni]);
                int c = cbase + ni * 16;
                if (s > v1) { v2 = v1; v1 = s; i1 = c; }
                else if (s > v2) v2 = s;
            }
            #pragma unroll
            for (int m = 1; m < 16; m <<= 1) {
                float ov1 = __shfl_xor(v1, m, 64);
                int   oi1 = __shfl_xor(i1, m, 64);
                float ov2 = __shfl_xor(v2, m, 64);
                float nv2 = fmaxf(fmaxf(v2, ov2), fminf(v1, ov1));
                if (ov1 > v1 || (ov1 == v1 && oi1 < i1)) { v1 = ov1; i1 = oi1; }
                v2 = nv2;
            }
            if (l15 == 0) sRed[wid * 128 + mi * 16 + rg * 4 + j] =
                make_float4(v1, __int_as_float(i1), v2, 0.f);
        }
    }
    __syncthreads();
    if (wc < 2) {
        int row = (wc << 6) + lane;
        float v1 = -3.4e38f, v2 = -3.4e38f; int i1 = 0x7fffffff;
        #pragma unroll
        for (int q = 0; q < 4; ++q) {
            float4 e = sRed[(wr * 4 + q) * 128 + row];
            float w1 = e.x; int jx = __float_as_int(e.y);
            float nv2 = fmaxf(fmaxf(v2, e.z), fminf(v1, w1));
            if (w1 > v1 || (w1 == v1 && jx < i1)) { v1 = w1; i1 = jx; }
            v2 = nv2;
        }
        int grow = bm + (wr << 7) + row;
        partials[(size_t)grow * 32 + bY] = make_float4(v1, __int_as_float(i1), v2, 0.f);
    }
}

// ---------------- combine per-row partials (32 tiles), decide rescue -----------
__global__ __launch_bounds__(256) void combine(const float4* __restrict__ partials,
                                               int* __restrict__ idx, float* __restrict__ idxf,
                                               float* __restrict__ rescueT) {
    int sub = threadIdx.x & 31;
    int row = blockIdx.x * 8 + (threadIdx.x >> 5);
    float4 p = partials[(size_t)row * 32 + sub];
    float v1 = p.x; int i1 = __float_as_int(p.y); float v2 = p.z;
    #pragma unroll
    for (int m = 1; m < 32; m <<= 1) {
        float ov1 = __shfl_xor(v1, m, 64);
        int   oi1 = __shfl_xor(i1, m, 64);
        float ov2 = __shfl_xor(v2, m, 64);
        float nv2 = fmaxf(fmaxf(v2, ov2), fminf(v1, ov1));
        if (ov1 > v1 || (ov1 == v1 && oi1 < i1)) { v1 = ov1; i1 = oi1; }
        v2 = nv2;
    }
    if (sub == 0) {
        idx[row] = i1;
        idxf[row] = (float)i1;
        rescueT[row] = (v1 - v2 <= MARGIN) ? (v1 - MARGIN) : 3.0e38f;
    }
}

// ---- exact rescue: recompute z-row from x (exact f32), rescan candidate tiles
__global__ __launch_bounds__(256) void rescue(const float* __restrict__ x,
                                              const float* __restrict__ W_in,
                                              const float* __restrict__ b_in,
                                              const float* __restrict__ embed,
                                              const float* __restrict__ esq,
                                              const float4* __restrict__ partials,
                                              const float* __restrict__ rescueT,
                                              int* __restrict__ idx, float* __restrict__ idxf) {
    int row = blockIdx.x;
    float t = rescueT[row];
    if (t > 1.0e38f) return;
    __shared__ __align__(16) float xrow[512];
    __shared__ __align__(16) float zrow[256];
    __shared__ float sv[256];
    __shared__ int   si[256];
    const int tid = threadIdx.x;
    xrow[tid] = x[(size_t)row * 512 + tid];
    xrow[tid + 256] = x[(size_t)row * 512 + 256 + tid];
    __syncthreads();
    // exact z[tid] = b_in[tid] + dot(W_in[tid], xrow)
    {
        float d = b_in[tid];
        const float4* wr4 = (const float4*)(W_in + (size_t)tid * 512);
        const float4* xr4 = (const float4*)xrow;
        #pragma unroll 8
        for (int k = 0; k < 128; ++k) {
            float4 w4 = wr4[k], x4 = xr4[k];
            d = fmaf(w4.x, x4.x, d); d = fmaf(w4.y, x4.y, d);
            d = fmaf(w4.z, x4.z, d); d = fmaf(w4.w, x4.w, d);
        }
        zrow[tid] = d;
    }
    __syncthreads();
    float bv = -3.4e38f; int bi = 0x7fffffff;
    for (int nt = 0; nt < 32; ++nt) {
        if (partials[(size_t)row * 32 + nt].x < t) continue;  // block-uniform
        int c = nt * 256 + tid;
        const float4* er = (const float4*)(embed + (size_t)c * 256);
        const float4* zr = (const float4*)zrow;
        float d = 0.f;
        #pragma unroll 4
        for (int k = 0; k < 64; ++k) {
            float4 e4 = er[k], z4 = zr[k];
            d = fmaf(e4.x, z4.x, d); d = fmaf(e4.y, z4.y, d);
            d = fmaf(e4.z, z4.z, d); d = fmaf(e4.w, z4.w, d);
        }
        float s = 2.f * d - esq[c];
        if (s > bv || (s == bv && c < bi)) { bv = s; bi = c; }
    }
    sv[tid] = bv; si[tid] = bi;
    __syncthreads();
    for (int s = 128; s; s >>= 1) {
        if (tid < s) {
            float ov = sv[tid + s]; int oi = si[tid + s];
            if (ov > sv[tid] || (ov == sv[tid] && oi < si[tid])) { sv[tid] = ov; si[tid] = oi; }
        }
        __syncthreads();
    }
    if (tid == 0) { idx[row] = si[0]; idxf[row] = (float)si[0]; }
}

// ====== gemm_out: out = embed[idx]@W_out^T + b_out, 4-term, BM=128 BN=128 =====
// K2=1024 (16 kt). A gathered from 2-term epack via idx: kt->(kt&3)|((kt>>3)<<2)
// B (woutpack 2-term): kt->kt&7.
__global__ __launch_bounds__(256, 2) void gemm_out_mfma(const short* __restrict__ epk,
                                                        const short* __restrict__ wpk,
                                                        const int* __restrict__ idx,
                                                        const float* __restrict__ b_out,
                                                        float* __restrict__ out) {
    __shared__ __align__(16) char smem[65536];   // per buf: A 16KB + B 16KB
    const int tid = threadIdx.x;
    const int lane = tid & 63, wid = tid >> 6;
    const int wr = wid >> 1, wc = wid & 1;
    const int l15 = lane & 15, rg = lane >> 4;
    const int bm = blockIdx.x << 7, bn = blockIdx.y << 7;
    const int g = tid & 7, rpb = tid >> 3;       // rpb 0..31

    const char* ebp = (const char*)epk;
    const char* wb = (const char*)wpk;
    const int sw = ((g ^ (rpb & 7)) << 4);
    size_t aoff[4], boff[4];
    #pragma unroll
    for (int it = 0; it < 4; ++it) {
        int c = idx[bm + it * 32 + rpb];
        aoff[it] = (size_t)c * 1024 + sw;
        boff[it] = (size_t)(bn + it * 32 + rpb) * 1024 + sw;
    }

    const int ax0 = ((rg ^ (l15 & 7)) << 4);
    const int ax1 = (((rg + 4) ^ (l15 & 7)) << 4);
    const char* aBase = smem + (wr * 64 + l15) * 128;
    const char* bBase = smem + 16384 + (wc * 64 + l15) * 128;

    f32x4 acc[4][4] = {};

#define GOUT_STAGE(BUF, KT) do { \
    size_t aK = (size_t)((((KT) & 3) | (((KT) >> 3) << 2))) * 128; \
    size_t bK = (size_t)((KT) & 7) * 128; \
    char* dA = smem + (BUF) * 32768 + (tid << 4); \
    char* dB = dA + 16384; \
    _Pragma("unroll") for (int it_ = 0; it_ < 4; ++it_) { \
        GLOAD16(ebp + aoff[it_] + aK, dA + it_ * 4096); \
        GLOAD16(wb + boff[it_] + bK, dB + it_ * 4096); } } while (0)

    GOUT_STAGE(0, 0);
    VMCNT(0);
    __syncthreads();
    #pragma unroll 1
    for (int kt = 0; kt < 16; ++kt) {
        const int buf = kt & 1;
        if (kt + 1 < 16) GOUT_STAGE(buf ^ 1, kt + 1);
        const char* aB = aBase + buf * 32768;
        const char* bB = bBase + buf * 32768;
        #pragma unroll
        for (int ks = 0; ks < 2; ++ks) {
            int ax = ks ? ax1 : ax0;
            short8 aF[4], bF[4];
            #pragma unroll
            for (int mi = 0; mi < 4; ++mi) aF[mi] = *(const short8*)(aB + mi * 2048 + ax);
            #pragma unroll
            for (int ni = 0; ni < 4; ++ni) bF[ni] = *(const short8*)(bB + ni * 2048 + ax);
            #pragma unroll
            for (int mi = 0; mi < 4; ++mi)
                #pragma unroll
                for (int ni = 0; ni < 4; ++ni)
                    acc[mi][ni] = __builtin_amdgcn_mfma_f32_16x16x32_bf16(aF[mi], bF[ni], acc[mi][ni], 0, 0, 0);
        }
        VMCNT(0);
        __syncthreads();
    }
    float bb[4];
    #pragma unroll
    for (int ni = 0; ni < 4; ++ni) bb[ni] = b_out[bn + wc * 64 + ni * 16 + l15];
    #pragma unroll
    for (int mi = 0; mi < 4; ++mi)
        #pragma unroll
        for (int ni = 0; ni < 4; ++ni)
            #pragma unroll
            for (int j = 0; j < 4; ++j) {
                int r = bm + wr * 64 + mi * 16 + rg * 4 + j;
                int c = bn + wc * 64 + ni * 16 + l15;
                out[(size_t)r * 512 + c] = acc[mi][ni][j] + bb[ni];
            }
}

// =================== fallback f32 path (ws too small) =========================
__global__ __launch_bounds__(256) void esq_kernel(const float* __restrict__ embed,
                                                  float* __restrict__ esq) {
    int wave = threadIdx.x >> 6, lane = threadIdx.x & 63;
    int c = (blockIdx.x << 2) + wave;
    float4 v = reinterpret_cast<const float4*>(embed + (size_t)c * CBD)[lane];
    float s = v.x * v.x + v.y * v.y + v.z * v.z + v.w * v.w;
    #pragma unroll
    for (int m = 32; m; m >>= 1) s += __shfl_xor(s, m, 64);
    if (!lane) esq[c] = s;
}

template <bool GATHER>
__global__ __launch_bounds__(256) void gemm_nt(const float* __restrict__ A,
                                               const float* __restrict__ B,
                                               const float* __restrict__ bias,
                                               const int* __restrict__ gather,
                                               float* __restrict__ C,
                                               int M, int N, int K) {
    __shared__ __align__(16) float sA[64][68];
    __shared__ __align__(16) float sB[64][68];
    const int tid = threadIdx.x;
    const int tx = tid & 15, ty = tid >> 4;
    const int bm = blockIdx.x << 6, bn = blockIdx.y << 6;
    float acc[4][4] = {};
    for (int k0 = 0; k0 < K; k0 += 64) {
        #pragma unroll
        for (int i = 0; i < 4; ++i) {
            int f = tid + (i << 8);
            int m = f >> 4;
            int k4 = (f & 15) << 2;
            long arow = bm + m;
            if (GATHER) arow = gather[arow];
            float4 v = *reinterpret_cast<const float4*>(A + arow * K + k0 + k4);
            sA[k4 + 0][m] = v.x; sA[k4 + 1][m] = v.y;
            sA[k4 + 2][m] = v.z; sA[k4 + 3][m] = v.w;
            float4 w = *reinterpret_cast<const float4*>(B + (long)(bn + m) * K + k0 + k4);
            sB[k4 + 0][m] = w.x; sB[k4 + 1][m] = w.y;
            sB[k4 + 2][m] = w.z; sB[k4 + 3][m] = w.w;
        }
        __syncthreads();
        #pragma unroll
        for (int kk = 0; kk < 64; ++kk) {
            float4 a = *reinterpret_cast<const float4*>(&sA[kk][ty << 2]);
            float4 b = *reinterpret_cast<const float4*>(&sB[kk][tx << 2]);
            float av[4] = {a.x, a.y, a.z, a.w};
            float bv[4] = {b.x, b.y, b.z, b.w};
            #pragma unroll
            for (int i = 0; i < 4; ++i)
                #pragma unroll
                for (int j = 0; j < 4; ++j)
                    acc[i][j] = fmaf(av[i], bv[j], acc[i][j]);
        }
        __syncthreads();
    }
    #pragma unroll
    for (int i = 0; i < 4; ++i) {
        long m = bm + (ty << 2) + i;
        #pragma unroll
        for (int j = 0; j < 4; ++j) {
            int n = bn + (tx << 2) + j;
            C[m * N + n] = acc[i][j] + bias[n];
        }
    }
}

__global__ __launch_bounds__(256) void score_argmax(const float* __restrict__ z,
                                                    const float* __restrict__ embed,
                                                    const float* __restrict__ esq,
                                                    int* __restrict__ idx_out,
                                                    float* __restrict__ idx_f32) {
    __shared__ __align__(16) float sZ[64][68];
    __shared__ __align__(16) float sE[64][68];
    const int tid = threadIdx.x;
    const int tx = tid & 15, ty = tid >> 4;
    const int bm = blockIdx.x << 6;
    float best[4];
    int bidx[4];
    #pragma unroll
    for (int i = 0; i < 4; ++i) { best[i] = -3.4e38f; bidx[i] = 0; }
    for (int ct = 0; ct < CBS; ct += 64) {
        float acc[4][4] = {};
        for (int k0 = 0; k0 < CBD; k0 += 64) {
            #pragma unroll
            for (int i = 0; i < 4; ++i) {
                int f = tid + (i << 8);
                int m = f >> 4;
                int k4 = (f & 15) << 2;
                float4 v = *reinterpret_cast<const float4*>(z + (long)(bm + m) * CBD + k0 + k4);
                sZ[k4 + 0][m] = v.x; sZ[k4 + 1][m] = v.y;
                sZ[k4 + 2][m] = v.z; sZ[k4 + 3][m] = v.w;
                float4 w = *reinterpret_cast<const float4*>(embed + (long)(ct + m) * CBD + k0 + k4);
                sE[k4 + 0][m] = w.x; sE[k4 + 1][m] = w.y;
                sE[k4 + 2][m] = w.z; sE[k4 + 3][m] = w.w;
            }
            __syncthreads();
            #pragma unroll
            for (int kk = 0; kk < 64; ++kk) {
                float4 a = *reinterpret_cast<const float4*>(&sZ[kk][ty << 2]);
                float4 b = *reinterpret_cast<const float4*>(&sE[kk][tx << 2]);
                float av[4] = {a.x, a.y, a.z, a.w};
                float bv[4] = {b.x, b.y, b.z, b.w};
                #pragma unroll
                for (int i = 0; i < 4; ++i)
                    #pragma unroll
                    for (int j = 0; j < 4; ++j)
                        acc[i][j] = fmaf(av[i], bv[j], acc[i][j]);
            }
            __syncthreads();
        }
        #pragma unroll
        for (int j = 0; j < 4; ++j) {
            int c = ct + (tx << 2) + j;
            float eq = esq[c];
            #pragma unroll
            for (int i = 0; i < 4; ++i) {
                float s = 2.0f * acc[i][j] - eq;
                if (s > best[i] || (s == best[i] && c < bidx[i])) { best[i] = s; bidx[i] = c; }
            }
        }
    }
    #pragma unroll
    for (int i = 0; i < 4; ++i) {
        float b = best[i];
        int bi = bidx[i];
        #pragma unroll
        for (int m = 1; m < 16; m <<= 1) {
            float ob = __shfl_xor(b, m, 64);
            int oi = __shfl_xor(bi, m, 64);
            if (ob > b || (ob == b && oi < bi)) { b = ob; bi = oi; }
        }
        if (tx == 0) {
            int row = bm + (ty << 2) + i;
            idx_out[row] = bi;
            idx_f32[row] = (float)bi;
        }
    }
}

extern "C" void kernel_launch(void* const* d_in, const int* in_sizes, int n_in,
                              void* d_out, int out_size, void* d_ws, size_t ws_size,
                              hipStream_t stream) {
    const float* x     = (const float*)d_in[0];
    const float* embed = (const float*)d_in[1];
    const float* W_in  = (const float*)d_in[2];
    const float* b_in  = (const float*)d_in[3];
    const float* W_out = (const float*)d_in[4];
    const float* b_out = (const float*)d_in[5];

    float* out_idx = (float*)d_out;              // [16384] indices as float
    float* out     = (float*)d_out + N_TOK;      // [16384,512]

    // workspace layout (main path)
    char* ws = (char*)d_ws;
    float*  esq      = (float*)ws;                                   // 32KB
    float*  rescueT  = (float*)(ws + 32768);                         // 64KB
    int*    idx      = (int*)(ws + 98304);                           // 64KB
    float4* partials = (float4*)(ws + 163840);                       // 8MB
    short*  xpack    = (short*)(ws + 163840 + 8388608);              // 33.55MB
    short*  zpack    = xpack + (size_t)N_TOK * 1024;                 // 16.78MB
    short*  epack    = zpack + (size_t)N_TOK * 512;                  // 8.39MB
    short*  winpk    = epack + (size_t)CBS * 512;                    // 0.52MB
    short*  wopk     = winpk + (size_t)CBD * 1024;                   // 0.52MB
    size_t need = (size_t)((char*)(wopk + (size_t)DIM * 512) - ws);

    if (ws_size >= need) {
        // pack inputs (2-term hi/lo bf16)
        pack_w<9><<<(N_TOK * DIM) / 256, 256, 0, stream>>>(x, xpack);
        pack_w<9><<<(CBD * DIM) / 256, 256, 0, stream>>>(W_in, winpk);
        pack_w<8><<<(DIM * CBD) / 256, 256, 0, stream>>>(W_out, wopk);
        prep_embed<<<CBS / 4, 256, 0, stream>>>(embed, esq, epack);
        // z = x@W_in^T + b_in (4-term MFMA), writes packed z
        gemm_in_mfma<<<dim3(N_TOK / 64, 2), 256, 0, stream>>>(xpack, winpk, b_in, zpack);
        // scores + per-tile top-2 (8-phase 256^2)
        score_mfma<<<2048, 512, 0, stream>>>(zpack, epack, esq, partials);
        // combine -> idx + rescue thresholds
        combine<<<N_TOK / 8, 256, 0, stream>>>(partials, idx, out_idx, rescueT);
        // exact rescue (recomputes z exactly from x)
        rescue<<<N_TOK, 256, 0, stream>>>(x, W_in, b_in, embed, esq, partials, rescueT, idx, out_idx);
        // out = embed[idx]@W_out^T + b_out (4-term MFMA, gathered staging)
        gemm_out_mfma<<<dim3(N_TOK / 128, 4), 256, 0, stream>>>(epack, wopk, idx, b_out, out);
    } else {
        // fallback: validated all-f32 path
        float* z   = (float*)d_ws;                   // 16MB
        float* es  = z + (size_t)N_TOK * CBD;
        int*   id  = (int*)(es + CBS);
        gemm_nt<false><<<dim3(N_TOK / 64, CBD / 64), 256, 0, stream>>>(
            x, W_in, b_in, nullptr, z, N_TOK, CBD, DIM);
        esq_kernel<<<CBS / 4, 256, 0, stream>>>(embed, es);
        score_argmax<<<N_TOK / 64, 256, 0, stream>>>(z, embed, es, id, out_idx);
        gemm_nt<true><<<dim3(N_TOK / 64, DIM / 64), 256, 0, stream>>>(
            embed, W_out, b_out, id, out, N_TOK, DIM, CBD);
    }
}